// Round 1
// baseline (8600.251 us; speedup 1.0000x reference)
//
#include <hip/hip_runtime.h>
#include <stdint.h>

// Problem constants
#define BB   128      // batch
#define DD   512      // input dim
#define HH   1024     // hidden dim
#define SS   512      // seq len
#define G4   4096     // 4*H gate rows
#define KTOT 1536     // D + H
#define NT_TOT 256    // G4/16 n-tiles
#define KK_TOT 48     // KTOT/32 k-chunks of 32
#define NT_FC  64     // H/16
#define KK_FC  32     // H/32

#define USTRIDE 264   // LDS U row stride in bf16 elems (256 + 8 pad)
#define GSTRIDE 72    // LDS gate row stride in f32 (64 + 8 pad, keeps float4 align)

typedef __attribute__((ext_vector_type(8))) short short8v;
typedef __attribute__((ext_vector_type(4))) float float4v;

__device__ __forceinline__ unsigned short f2bf(float f) {
    union { float f; unsigned int u; } v; v.f = f;
    unsigned int u = v.u;
    unsigned int r = u + 0x7FFFu + ((u >> 16) & 1u);   // RNE
    return (unsigned short)(r >> 16);
}

// ---------------------------------------------------------------------------
// Pack W = [W_ih | W_hh] rows permuted to r = 4*j + q (j=hidden unit, q=gate)
// into bf16 MFMA-fragment order: wp[((ntile*KK_TOT + kk)*64 + lane)*8 + i]
// holds W[r = ntile*16 + (lane&15)][k = kk*32 + (lane>>4)*8 + i].
// ---------------------------------------------------------------------------
__global__ void pack_w_kernel(const float* __restrict__ W_ih,
                              const float* __restrict__ W_hh,
                              unsigned short* __restrict__ wp) {
    int idx = blockIdx.x * 256 + threadIdx.x;           // (ntile, kk, lane)
    if (idx >= NT_TOT * KK_TOT * 64) return;
    int lane  = idx & 63;
    int kk    = (idx >> 6) % KK_TOT;
    int ntile = idx / (64 * KK_TOT);
    int r = ntile * 16 + (lane & 15);
    int j = r >> 2, q = r & 3;
    int orow = q * HH + j;
    int kbase = kk * 32 + (lane >> 4) * 8;
    short8v ov;
#pragma unroll
    for (int i = 0; i < 8; ++i) {
        int k = kbase + i;
        float v = (k < DD) ? W_ih[(size_t)orow * DD + k]
                           : W_hh[(size_t)orow * HH + (k - DD)];
        ov[i] = (short)f2bf(v);
    }
    *(short8v*)&wp[(size_t)idx * 8] = ov;
}

// fc_w [H][H] -> bf16 fragment order (no row permutation needed)
__global__ void pack_fc_kernel(const float* __restrict__ fc_w,
                               unsigned short* __restrict__ wfc) {
    int idx = blockIdx.x * 256 + threadIdx.x;
    if (idx >= NT_FC * KK_FC * 64) return;
    int lane  = idx & 63;
    int kk    = (idx >> 6) % KK_FC;
    int ntile = idx / (64 * KK_FC);
    int o = ntile * 16 + (lane & 15);
    int kbase = kk * 32 + (lane >> 4) * 8;
    short8v ov;
#pragma unroll
    for (int i = 0; i < 8; ++i)
        ov[i] = (short)f2bf(fc_w[(size_t)o * HH + kbase + i]);
    *(short8v*)&wfc[(size_t)idx * 8] = ov;
}

// zero c and h0, pack bias bp[4j+q] = b_ih[qH+j] + b_hh[qH+j]
__global__ void init_kernel(const float* __restrict__ b_ih,
                            const float* __restrict__ b_hh,
                            float* __restrict__ cst,
                            unsigned short* __restrict__ h0,
                            float* __restrict__ bp) {
    int i = blockIdx.x * 256 + threadIdx.x;             // grid covers B*H
    if (i < BB * HH) { cst[i] = 0.f; h0[i] = 0; }
    if (i < G4) {
        int j = i >> 2, q = i & 3;
        bp[i] = b_ih[q * HH + j] + b_hh[q * HH + j];
    }
}

// ---------------------------------------------------------------------------
// One LSTM step: gates = [x_t | h_in] @ Wp^T (+bias in epilogue), fused
// activation + state update. Grid 128 = 2 M-groups x 64 N-groups.
// Each WG: M=64 batches, N=64 packed gate rows (= 16 hidden units).
// 4 waves as 2x2, wave tile 32x32, MFMA 16x16x32 bf16, K chunks of 256 in LDS.
// ---------------------------------------------------------------------------
__launch_bounds__(256)
__global__ void lstm_step_kernel(const float* __restrict__ x,
                                 const unsigned short* __restrict__ wp,
                                 const float* __restrict__ bp,
                                 float* __restrict__ cst,
                                 const unsigned short* __restrict__ h_in,
                                 unsigned short* __restrict__ h_out,
                                 int t) {
    __shared__ __align__(16) char smem[64 * USTRIDE * 2];   // 33792 B
    unsigned short* ulds = (unsigned short*)smem;
    float* glds = (float*)smem;                             // aliased after barrier

    const int tid = threadIdx.x;
    const int bid = blockIdx.x;
    const int mg = bid >> 6;        // 0..1  (W-slice sharers 64 apart -> same XCD)
    const int ng = bid & 63;        // 0..63
    const int m0 = mg * 64;
    const int lane = tid & 63;
    const int wave = tid >> 6;
    const int wm = wave >> 1, wn = wave & 1;

    float4v acc[2][2] = {};

    for (int c = 0; c < 6; ++c) {           // 6 K-chunks of 256
        __syncthreads();                    // previous chunk fully consumed
        // ---- stage U chunk [64][256] bf16 into LDS ----
        for (int it = 0; it < 16; ++it) {
            int v = tid + 256 * it;         // 0..4095 vec4 groups
            int row = v >> 6;
            int kl = (v & 63) * 4;
            int m = m0 + row;
            ushort4 w4;
            if (c < 2) {                    // x_t region, fp32 -> bf16
                float4 xv = *(const float4*)&x[((size_t)m * SS + t) * DD + c * 256 + kl];
                w4.x = f2bf(xv.x); w4.y = f2bf(xv.y);
                w4.z = f2bf(xv.z); w4.w = f2bf(xv.w);
            } else {                        // h region, already bf16
                w4 = *(const ushort4*)&h_in[(size_t)m * HH + (c - 2) * 256 + kl];
            }
            *(ushort4*)&ulds[row * USTRIDE + kl] = w4;
        }
        __syncthreads();
        // ---- 8 MFMA k-steps of K=32 ----
#pragma unroll
        for (int kk = 0; kk < 8; ++kk) {
            int kkg = c * 8 + kk;
            short8v a[2], b[2];
#pragma unroll
            for (int mt = 0; mt < 2; ++mt) {
                int row = wm * 32 + mt * 16 + (lane & 15);
                a[mt] = *(const short8v*)&ulds[row * USTRIDE + kk * 32 + (lane >> 4) * 8];
            }
#pragma unroll
            for (int nt = 0; nt < 2; ++nt) {
                int ntile = ng * 4 + wn * 2 + nt;
                b[nt] = *(const short8v*)&wp[(((size_t)ntile * KK_TOT + kkg) * 64 + lane) * 8];
            }
#pragma unroll
            for (int mt = 0; mt < 2; ++mt)
#pragma unroll
                for (int nt = 0; nt < 2; ++nt)
                    acc[mt][nt] = __builtin_amdgcn_mfma_f32_16x16x32_bf16(
                        a[mt], b[nt], acc[mt][nt], 0, 0, 0);
        }
    }
    __syncthreads();
    // ---- dump gates (fp32) to LDS; C/D layout: col=lane&15, row=(lane>>4)*4+r ----
#pragma unroll
    for (int mt = 0; mt < 2; ++mt)
#pragma unroll
        for (int nt = 0; nt < 2; ++nt)
#pragma unroll
            for (int r = 0; r < 4; ++r) {
                int mrow = wm * 32 + mt * 16 + (lane >> 4) * 4 + r;
                int ncol = wn * 32 + nt * 16 + (lane & 15);
                glds[mrow * GSTRIDE + ncol] = acc[mt][nt][r];
            }
    __syncthreads();
    // ---- fused activation + state update: 64 m x 16 units per WG ----
    int jl = tid & 15;
    int mb = tid >> 4;                      // 0..15
#pragma unroll
    for (int rep = 0; rep < 4; ++rep) {
        int ml = mb + rep * 16;             // 0..63
        int j = ng * 16 + jl;
        int mglob = m0 + ml;
        float4 gv = *(float4*)&glds[ml * GSTRIDE + jl * 4];   // i,f,g,o preacts
        float4 bb = *(const float4*)&bp[j * 4];
        float ig = 1.f / (1.f + __expf(-(gv.x + bb.x)));
        float fg = 1.f / (1.f + __expf(-(gv.y + bb.y)));
        float gg = tanhf(gv.z + bb.z);
        float og = 1.f / (1.f + __expf(-(gv.w + bb.w)));
        float cold = cst[(size_t)mglob * HH + j];
        float cnew = fg * cold + ig * gg;
        float hh = og * tanhf(cnew);
        cst[(size_t)mglob * HH + j] = cnew;
        h_out[(size_t)mglob * HH + j] = f2bf(hh);
    }
}

// ---------------------------------------------------------------------------
// out[128,1024] = h_fin @ fc_w^T + fc_b  (fp32 out). 32 WGs: 2 Mg x 16 Ng.
// ---------------------------------------------------------------------------
__launch_bounds__(256)
__global__ void fc_kernel(const unsigned short* __restrict__ hfin,
                          const unsigned short* __restrict__ wfc,
                          const float* __restrict__ fc_b,
                          float* __restrict__ out) {
    __shared__ __align__(16) char smem[64 * USTRIDE * 2];
    unsigned short* ulds = (unsigned short*)smem;
    const int tid = threadIdx.x, bid = blockIdx.x;
    const int mg = bid >> 4;       // 0..1
    const int ng = bid & 15;       // 0..15
    const int m0 = mg * 64;
    const int lane = tid & 63, wave = tid >> 6;
    const int wm = wave >> 1, wn = wave & 1;

    float4v acc[2][2] = {};
    for (int c = 0; c < 4; ++c) {           // K=1024 in 4 chunks
        __syncthreads();
        for (int it = 0; it < 16; ++it) {
            int v = tid + 256 * it;
            int row = v >> 6;
            int kl = (v & 63) * 4;
            ushort4 hv = *(const ushort4*)&hfin[(size_t)(m0 + row) * HH + c * 256 + kl];
            *(ushort4*)&ulds[row * USTRIDE + kl] = hv;
        }
        __syncthreads();
#pragma unroll
        for (int kk = 0; kk < 8; ++kk) {
            int kkg = c * 8 + kk;
            short8v a[2], b[2];
#pragma unroll
            for (int mt = 0; mt < 2; ++mt) {
                int row = wm * 32 + mt * 16 + (lane & 15);
                a[mt] = *(const short8v*)&ulds[row * USTRIDE + kk * 32 + (lane >> 4) * 8];
            }
#pragma unroll
            for (int nt = 0; nt < 2; ++nt) {
                int ntile = ng * 4 + wn * 2 + nt;
                b[nt] = *(const short8v*)&wfc[(((size_t)ntile * KK_FC + kkg) * 64 + lane) * 8];
            }
#pragma unroll
            for (int mt = 0; mt < 2; ++mt)
#pragma unroll
                for (int nt = 0; nt < 2; ++nt)
                    acc[mt][nt] = __builtin_amdgcn_mfma_f32_16x16x32_bf16(
                        a[mt], b[nt], acc[mt][nt], 0, 0, 0);
        }
    }
#pragma unroll
    for (int mt = 0; mt < 2; ++mt)
#pragma unroll
        for (int nt = 0; nt < 2; ++nt)
#pragma unroll
            for (int r = 0; r < 4; ++r) {
                int mrow = m0 + wm * 32 + mt * 16 + (lane >> 4) * 4 + r;
                int o = ng * 64 + wn * 32 + nt * 16 + (lane & 15);
                out[(size_t)mrow * HH + o] = acc[mt][nt][r] + fc_b[o];
            }
}

// ---------------------------------------------------------------------------
extern "C" void kernel_launch(void* const* d_in, const int* in_sizes, int n_in,
                              void* d_out, int out_size, void* d_ws, size_t ws_size,
                              hipStream_t stream) {
    const float* x    = (const float*)d_in[0];
    const float* W_ih = (const float*)d_in[1];
    const float* W_hh = (const float*)d_in[2];
    const float* b_ih = (const float*)d_in[3];
    const float* b_hh = (const float*)d_in[4];
    const float* fc_w = (const float*)d_in[5];
    const float* fc_b = (const float*)d_in[6];
    float* out = (float*)d_out;

    char* ws = (char*)d_ws;
    size_t off = 0;
    unsigned short* wp  = (unsigned short*)(ws + off); off += (size_t)NT_TOT * KK_TOT * 64 * 8 * 2; // 12 MB
    unsigned short* wfc = (unsigned short*)(ws + off); off += (size_t)NT_FC * KK_FC * 64 * 8 * 2;   // 2 MB
    float* bp  = (float*)(ws + off); off += (size_t)G4 * 4;
    float* cst = (float*)(ws + off); off += (size_t)BB * HH * 4;
    unsigned short* hbuf0 = (unsigned short*)(ws + off); off += (size_t)BB * HH * 2;
    unsigned short* hbuf1 = (unsigned short*)(ws + off); off += (size_t)BB * HH * 2;
    if (ws_size < off) return;   // workspace too small — fail visibly, don't scribble

    pack_w_kernel<<<3072, 256, 0, stream>>>(W_ih, W_hh, wp);
    pack_fc_kernel<<<512, 256, 0, stream>>>(fc_w, wfc);
    init_kernel<<<512, 256, 0, stream>>>(b_ih, b_hh, cst, hbuf0, bp);

    for (int t = 0; t < SS; ++t) {
        const unsigned short* hi = (t & 1) ? hbuf1 : hbuf0;
        unsigned short* ho       = (t & 1) ? hbuf0 : hbuf1;
        lstm_step_kernel<<<128, 256, 0, stream>>>(x, wp, bp, cst, hi, ho, t);
    }
    // S=512 even -> final h lives in hbuf0
    fc_kernel<<<32, 256, 0, stream>>>(hbuf0, wfc, fc_b, out);
}